// Round 2
// baseline (511.025 us; speedup 1.0000x reference)
//
#include <hip/hip_runtime.h>
#include <hip/hip_bf16.h>
#include <math.h>

#define Nn 32
#define Dd 512
#define Pp 4096
#define Kk 64
#define SEG 16           // p-segments (blocks per n)
#define PXB 256          // px per block
#define PT 64            // px per p-tile
static constexpr float EPSF = 1e-12f;

typedef short short8 __attribute__((ext_vector_type(8)));
typedef short short4v __attribute__((ext_vector_type(4)));
typedef float floatx4 __attribute__((ext_vector_type(4)));

static __device__ __forceinline__ int f2b2(float a, float b) {
  __hip_bfloat162 h = __float22bfloat162_rn(float2{a, b});
  int r; __builtin_memcpy(&r, &h, 4); return r;
}
static __device__ __forceinline__ short8 pack8(const float* v) {
  union { short8 s; int i[4]; } u;
  u.i[0] = f2b2(v[0], v[1]); u.i[1] = f2b2(v[2], v[3]);
  u.i[2] = f2b2(v[4], v[5]); u.i[3] = f2b2(v[6], v[7]);
  return u.s;
}
static __device__ __forceinline__ short f2b1(float f) {
  unsigned u = __float_as_uint(f);
  return (short)((u + 0x7FFFu + ((u >> 16) & 1u)) >> 16);
}
static __device__ __forceinline__ float b2f(short s) {
  return __uint_as_float(((unsigned)(unsigned short)s) << 16);
}

// ---------------------------------------------------------------------------
// K0: prepack w -> bf16 B-fragment order wp[chunk][k][q][8] + zero asum.
// ---------------------------------------------------------------------------
__global__ __launch_bounds__(256) void k_wpack(
    const float* __restrict__ w, float* __restrict__ asum,
    short* __restrict__ wp)
{
  int id = blockIdx.x * 256 + threadIdx.x;     // 4*256 = 1024 threads
  if (id >= 1024) return;
  asum[id] = 0.f; asum[id + 1024] = 0.f;       // zero asum[2048]
  int chunk = id >> 6, k = id & 63;
  const float* src = w + (size_t)k * Dd + chunk * 32;
  short* dst = wp + ((size_t)(chunk * 64 + k)) * 32;
#pragma unroll
  for (int q = 0; q < 4; ++q) {
    float v[8];
    *(float4*)&v[0] = *(const float4*)(src + q * 8);
    *(float4*)&v[4] = *(const float4*)(src + q * 8 + 4);
    *(short8*)(dst + q * 8) = pack8(v);
  }
}

// ---------------------------------------------------------------------------
// K1: FUSED norm + logits + softmax + vlad-partial.
// grid: 32 n x 16 segs = 512 blocks x 512 thr (8 waves); 2 blocks/CU target
// -> 4 waves/SIMD (needs <=128 VGPR, enforced by launch_bounds).
// GEMM1: wave (wg = wave&3 -> 16-px group, kh = wave>>2 -> 32-k half).
//   A-frags from global scalar loads (kh twins dup, L1-hot); B from wp.
//   x simultaneously staged bf16 into LDS xb (XOR-swizzled) for GEMM2.
// Softmax: no max-subtraction (|logit| <= ||w_k|| ~ 1.2, exp-safe);
//   wave-local pc-reduction, cross-kh sum merge via LDS ssum + barrier.
// GEMM2: all 8 waves, d-split 64/wave, acc2[4][4] = 64 VGPRs.
// ---------------------------------------------------------------------------
__global__ __launch_bounds__(512, 4) void k_fused(
    const float* __restrict__ x, const short* __restrict__ wp,
    float* __restrict__ asum, short* __restrict__ vpart)
{
  constexpr int XS = 64;   // xb row stride (shorts), XOR-swizzled columns
  constexpr int AS = 72;   // a_s row stride (even 8-slot bank spread)
  __shared__ short xb[Dd * XS];      // 64 KB  x tile bf16 [d][px] swizzled
  __shared__ short as_[Kk * AS];     // 9 KB   a*inv bf16  [k][px]
  __shared__ float invs[PT];
  __shared__ float ssum[2 * PT];     // per-kh-half softmax denominators

  const int tid = threadIdx.x;
  const int n = blockIdx.x >> 4, seg = blockIdx.x & 15;
  const int wave = tid >> 6, lane = tid & 63;
  const int wg = wave & 3, kh = wave >> 2;
  const int q = lane >> 4, pc = lane & 15;
  const int sd = tid >> 4, sc = tid & 15;            // stage: 32 rows x 16 f4
  const int swcol = (sc * 4) ^ ((sd & 7) << 3);      // swizzled stage col
  const int rdxor = (pc & 7) << 3;                   // swizzle for GEMM2 reads

  floatx4 acc2[4][4];                // [k-tile][d-tile] = 64 VGPRs
#pragma unroll
  for (int a = 0; a < 4; ++a)
#pragma unroll
    for (int b = 0; b < 4; ++b) acc2[a][b] = floatx4{0.f, 0.f, 0.f, 0.f};
  float asr[2] = {0.f, 0.f};         // asum partials (k = kh*32 + t*16 + pc)

  const float* xn = x + (size_t)n * Dd * Pp;

  for (int pt = 0; pt < PXB / PT; ++pt) {
    const int p0 = seg * PXB + pt * PT;
    __syncthreads();                 // xb/as_/ssum free to overwrite

    floatx4 acc1[2];
    acc1[0] = floatx4{0.f, 0.f, 0.f, 0.f};
    acc1[1] = floatx4{0.f, 0.f, 0.f, 0.f};
    float sq = 0.f;

    const float* xa = xn + (size_t)(q * 8) * Pp + p0 + wg * 16 + pc;
    const float* xs = xn + (size_t)sd * Pp + p0 + sc * 4;

    for (int dc = 0; dc < Dd; dc += 32) {
      // stage: one float4/thread, bf16 pack, swizzled LDS write
      float4 u0 = *(const float4*)xs;
      *(int2*)&xb[(dc + sd) * XS + swcol] =
          int2{ f2b2(u0.x, u0.y), f2b2(u0.z, u0.w) };
      xs += (size_t)32 * Pp;
      // A-frag: 8 scalar x loads (64B segments, L1-hot vs stage), ssq piggyback
      float v[8];
#pragma unroll
      for (int j = 0; j < 8; ++j) {
        float a = xa[(size_t)j * Pp];
        v[j] = a; sq += a * a;
      }
      xa += (size_t)32 * Pp;
      short8 af = pack8(v);
      // B-frags for this wave's k-half (L2-hot) + MFMA
      const short* wc = wp + (size_t)(dc >> 5) * 2048 + kh * 1024 + pc * 32 + q * 8;
      acc1[0] = __builtin_amdgcn_mfma_f32_16x16x32_bf16(
          af, *(const short8*)wc, acc1[0], 0, 0, 0);
      acc1[1] = __builtin_amdgcn_mfma_f32_16x16x32_bf16(
          af, *(const short8*)(wc + 512), acc1[1], 0, 0, 0);
    }

    // per-pixel inv-norm (both kh twins compute identical values; benign dup)
    {
      float tsum = sq;
      tsum += __shfl_xor(tsum, 16);
      tsum += __shfl_xor(tsum, 32);
      if (q == 0) invs[wg * 16 + pc] = 1.f / fmaxf(sqrtf(tsum), EPSF);
    }
    float ivr[4], e0[4], e1[4];
#pragma unroll
    for (int r = 0; r < 4; ++r) ivr[r] = invs[wg * 16 + q * 4 + r];

    // softmax part 1: exp (no max shift; logits bounded by ||w_k||),
    // wave-local sum over this kh's 32 k's, stash per-half denominator
#pragma unroll
    for (int r = 0; r < 4; ++r) {
      e0[r] = __expf(acc1[0][r] * ivr[r]);
      e1[r] = __expf(acc1[1][r] * ivr[r]);
      float s = e0[r] + e1[r];
      s += __shfl_xor(s, 1);
      s += __shfl_xor(s, 2);
      s += __shfl_xor(s, 4);
      s += __shfl_xor(s, 8);
      if (pc == 0) ssum[kh * PT + wg * 16 + q * 4 + r] = s;
    }
    __syncthreads();                 // ssum ready

    // softmax part 2: merge halves, write a*inv to as_, asum partials
#pragma unroll
    for (int r = 0; r < 4; ++r) {
      const int px = wg * 16 + q * 4 + r;
      float si = 1.f / (ssum[px] + ssum[PT + px]);
      float a0 = e0[r] * si, a1 = e1[r] * si;
      asr[0] += a0; asr[1] += a1;
      as_[(kh * 32 + pc) * AS + px]      = f2b1(a0 * ivr[r]);
      as_[(kh * 32 + 16 + pc) * AS + px] = f2b1(a1 * ivr[r]);
    }
    __syncthreads();                 // as_ + xb complete

    // GEMM2: vlad acc += a_s[k][p] * xb[d][p]; wave owns d = wave*64..+63
#pragma unroll
    for (int c = 0; c < 2; ++c) {    // px-chunks of 32
      short8 af2[4];
#pragma unroll
      for (int kt = 0; kt < 4; ++kt)
        af2[kt] = *(const short8*)&as_[(kt * 16 + pc) * AS + c * 32 + q * 8];
#pragma unroll
      for (int s2 = 0; s2 < 4; ++s2) {
        const int row = (wave << 6) + s2 * 16 + pc;
        short8 bf2 = *(const short8*)&xb[row * XS + ((c * 32 + q * 8) ^ rdxor)];
#pragma unroll
        for (int kt = 0; kt < 4; ++kt)
          acc2[kt][s2] = __builtin_amdgcn_mfma_f32_16x16x32_bf16(
              af2[kt], bf2, acc2[kt][s2], 0, 0, 0);
      }
    }
  }

  // epilogue: asum atomics + vpart bf16 stores
#pragma unroll
  for (int t = 0; t < 2; ++t) {
    float v = asr[t];
    v += __shfl_xor(v, 16);
    v += __shfl_xor(v, 32);
    if (q == 0) atomicAdd(&asum[n * Kk + kh * 32 + t * 16 + pc], v);
  }
  short* vb = vpart + ((size_t)(seg * Nn + n) * Kk) * Dd;
#pragma unroll
  for (int kt = 0; kt < 4; ++kt)
#pragma unroll
    for (int s2 = 0; s2 < 4; ++s2)
#pragma unroll
      for (int r = 0; r < 4; ++r)
        vb[(size_t)(kt * 16 + q * 4 + r) * Dd + (wave << 6) + s2 * 16 + pc] =
            f2b1(acc2[kt][s2][r]);
}

// ---------------------------------------------------------------------------
// K2: combine 16 bf16 partials, subtract asum*centroid, intra-normalize,
// fold global 1/sqrt(K)=0.125 (rows are unit-norm after intra-normalization,
// so the global L2 norm is exactly sqrt(K)). grid: Nn*Kk blocks x 128 thr.
// ---------------------------------------------------------------------------
__global__ __launch_bounds__(128) void k_intra(
    const short* __restrict__ vpart, const float* __restrict__ asum,
    const float* __restrict__ cent, float* __restrict__ out)
{
  __shared__ float red[2];
  const int nk = blockIdx.x;
  const int n = nk >> 6, k = nk & 63;
  const int tid = threadIdx.x;
  const int d = tid * 4;

  float4 v = {0.f, 0.f, 0.f, 0.f};
#pragma unroll
  for (int ps = 0; ps < SEG; ++ps) {
    short4v t = *(const short4v*)&vpart[((size_t)(ps * Nn + n) * Kk + k) * Dd + d];
    v.x += b2f(t[0]); v.y += b2f(t[1]); v.z += b2f(t[2]); v.w += b2f(t[3]);
  }
  float s = asum[n * Kk + k];
  float4 c = *(const float4*)&cent[(size_t)k * Dd + d];
  v.x -= s * c.x; v.y -= s * c.y; v.z -= s * c.z; v.w -= s * c.w;

  float qq = v.x * v.x + v.y * v.y + v.z * v.z + v.w * v.w;
#pragma unroll
  for (int off = 32; off; off >>= 1) qq += __shfl_down(qq, off);
  if ((tid & 63) == 0) red[tid >> 6] = qq;
  __syncthreads();
  float norm = sqrtf(red[0] + red[1]);
  float r = 0.125f / fmaxf(norm, EPSF);   // intra-norm * global 1/sqrt(64)
  v.x *= r; v.y *= r; v.z *= r; v.w *= r;
  *(float4*)&out[(size_t)n * (Kk * Dd) + (size_t)k * Dd + d] = v;
}

extern "C" void kernel_launch(void* const* d_in, const int* in_sizes, int n_in,
                              void* d_out, int out_size, void* d_ws, size_t ws_size,
                              hipStream_t stream) {
  (void)in_sizes; (void)n_in; (void)out_size; (void)ws_size;
  const float* x    = (const float*)d_in[0];   // [N,D,H,W]
  const float* w    = (const float*)d_in[1];   // [K,D]
  const float* cent = (const float*)d_in[2];   // [K,D]
  float* out = (float*)d_out;

  // ws: asum f32[2048] | vpart bf16 [SEG*N*K*D] (33.5 MB) | wp bf16
  float* asum  = (float*)d_ws;
  short* vpart = (short*)(asum + Nn * Kk);
  short* wpk   = vpart + (size_t)SEG * Nn * Kk * Dd;

  k_wpack<<<4, 256, 0, stream>>>(w, asum, wpk);
  k_fused<<<Nn * SEG, 512, 0, stream>>>(x, wpk, asum, vpart);
  k_intra<<<Nn * Kk, 128, 0, stream>>>(vpart, asum, cent, out);
}

// Round 3
// 398.878 us; speedup vs baseline: 1.2812x; 1.2812x over previous
//
#include <hip/hip_runtime.h>
#include <hip/hip_bf16.h>
#include <math.h>

#define Nn 32
#define Dd 512
#define Pp 4096
#define Kk 64
#define SEG 16           // p-segments (blocks per n)
#define PXB 256          // px per block
#define PT 64            // px per p-tile
static constexpr float EPSF = 1e-12f;

typedef short short8 __attribute__((ext_vector_type(8)));
typedef short short4v __attribute__((ext_vector_type(4)));
typedef float floatx4 __attribute__((ext_vector_type(4)));

static __device__ __forceinline__ int f2b2(float a, float b) {
  __hip_bfloat162 h = __float22bfloat162_rn(float2{a, b});
  int r; __builtin_memcpy(&r, &h, 4); return r;
}
static __device__ __forceinline__ short8 pack8(const float* v) {
  union { short8 s; int i[4]; } u;
  u.i[0] = f2b2(v[0], v[1]); u.i[1] = f2b2(v[2], v[3]);
  u.i[2] = f2b2(v[4], v[5]); u.i[3] = f2b2(v[6], v[7]);
  return u.s;
}
static __device__ __forceinline__ short f2b1(float f) {
  unsigned u = __float_as_uint(f);
  return (short)((u + 0x7FFFu + ((u >> 16) & 1u)) >> 16);
}
static __device__ __forceinline__ float b2f(short s) {
  return __uint_as_float(((unsigned)(unsigned short)s) << 16);
}

// ---------------------------------------------------------------------------
// K0: prepack w -> bf16 B-fragment order wp[chunk][k][q][8] + zero asum.
// ---------------------------------------------------------------------------
__global__ __launch_bounds__(256) void k_wpack(
    const float* __restrict__ w, float* __restrict__ asum,
    short* __restrict__ wp)
{
  int id = blockIdx.x * 256 + threadIdx.x;     // 4*256 = 1024 threads
  if (id >= 1024) return;
  asum[id] = 0.f; asum[id + 1024] = 0.f;       // zero asum[2048]
  int chunk = id >> 6, k = id & 63;
  const float* src = w + (size_t)k * Dd + chunk * 32;
  short* dst = wp + ((size_t)(chunk * 64 + k)) * 32;
#pragma unroll
  for (int q = 0; q < 4; ++q) {
    float v[8];
    *(float4*)&v[0] = *(const float4*)(src + q * 8);
    *(float4*)&v[4] = *(const float4*)(src + q * 8 + 4);
    *(short8*)(dst + q * 8) = pack8(v);
  }
}

// ---------------------------------------------------------------------------
// K1: FUSED norm + logits + softmax + vlad-partial.
// grid: 32 n x 16 segs = 512 blocks x 256 thr; 2 blocks/CU.
// launch_bounds(256,2): 2 waves/SIMD -> 256-reg/wave budget. This is the
// round-0 structure: the wide register budget lets the compiler keep the
// dc-loop's 11 global loads/iter deeply in flight (ILP), which beats the
// 4-waves/SIMD variant that register-starved the pipeliner (round-2: 242us,
// VGPR_Count=64, everything idle).
// Per 64-px tile: GEMM1 (A = x scalar loads, B = wp bf16, L1/L2-hot) with x
// simultaneously re-read as float4 (L1-hot) and stashed bf16 in LDS xb
// (XOR-swizzled cols). Softmax in-register per wave, max-less (logits
// bounded by ||w_k|| ~ 1.13, exp-safe); a*inv -> LDS a_s. GEMM2 from LDS
// only, acc [64k x 128d] per wave in VGPRs across all 4 tiles.
// ---------------------------------------------------------------------------
__global__ __launch_bounds__(256, 2) void k_fused(
    const float* __restrict__ x, const short* __restrict__ wp,
    float* __restrict__ asum, short* __restrict__ vpart)
{
  constexpr int XS = 64;   // xb row stride (shorts), XOR-swizzled columns
  constexpr int AS = 72;   // a_s row stride (16B-aligned rows)
  __shared__ short xb[Dd * XS];      // 64 KB  x tile bf16 [d][px] swizzled
  __shared__ short as_[Kk * AS];     // 9 KB   a*inv bf16  [k][px]
  __shared__ float invs[PT];

  const int tid = threadIdx.x;
  const int n = blockIdx.x >> 4, seg = blockIdx.x & 15;
  const int wave = tid >> 6, lane = tid & 63;
  const int q = lane >> 4, pc = lane & 15;
  const int sd = tid >> 3, sc = tid & 7;           // stage loader coords
  const int swc = (sc * 8) ^ ((sd & 7) << 3);      // swizzled stage col
  const int rdxor = (pc & 7) << 3;                 // swizzle for GEMM2 reads

  floatx4 acc2[4][8];                // [k-tile][d-tile] = 128 regs
#pragma unroll
  for (int t = 0; t < 4; ++t)
#pragma unroll
    for (int s2 = 0; s2 < 8; ++s2) acc2[t][s2] = floatx4{0.f, 0.f, 0.f, 0.f};
  float asr[4] = {0.f, 0.f, 0.f, 0.f};   // asum partials (k = t*16+pc)

  const float* xn = x + (size_t)n * Dd * Pp;

  for (int pt = 0; pt < PXB / PT; ++pt) {
    const int p0 = seg * PXB + pt * PT;
    __syncthreads();                 // xb/a_s free to overwrite

    floatx4 acc1[4];
#pragma unroll
    for (int t = 0; t < 4; ++t) acc1[t] = floatx4{0.f, 0.f, 0.f, 0.f};
    float sq = 0.f;

    const float* xa = xn + (size_t)(q * 8) * Pp + p0 + wave * 16 + pc;
    const float* xs = xn + (size_t)sd * Pp + p0 + sc * 8;

    for (int dc = 0; dc < Dd; dc += 32) {
      // stage: re-read (L1-hot) as float4, stash bf16 tile [d][px] swizzled
      float4 u0 = *(const float4*)xs;
      float4 u1 = *(const float4*)(xs + 4);
      int2 w0 = { f2b2(u0.x, u0.y), f2b2(u0.z, u0.w) };
      int2 w1 = { f2b2(u1.x, u1.y), f2b2(u1.z, u1.w) };
      *(int2*)&xb[(dc + sd) * XS + swc] = w0;
      *(int2*)&xb[(dc + sd) * XS + swc + 4] = w1;
      xs += (size_t)32 * Pp;
      // A-frag: 8 scalar x loads (coalesced 64B segments), ssq piggyback
      float v[8];
#pragma unroll
      for (int j = 0; j < 8; ++j) {
        float a = xa[(size_t)j * Pp];
        v[j] = a; sq += a * a;
      }
      xa += (size_t)32 * Pp;
      short8 af = pack8(v);
      // B-frags from prepacked w (L2-hot) + MFMA
      const short* wc = wp + (size_t)(dc >> 5) * 2048 + pc * 32 + q * 8;
#pragma unroll
      for (int t = 0; t < 4; ++t) {
        short8 bf = *(const short8*)(wc + t * 512);
        acc1[t] = __builtin_amdgcn_mfma_f32_16x16x32_bf16(af, bf, acc1[t], 0, 0, 0);
      }
    }

    // per-pixel inv-norm (lane pc owns px = wave*16+pc partial over its q-quarter)
    {
      float tsum = sq;
      tsum += __shfl_xor(tsum, 16);
      tsum += __shfl_xor(tsum, 32);
      if (q == 0) invs[wave * 16 + pc] = 1.f / fmaxf(sqrtf(tsum), EPSF);
    }
    float ivr[4];
#pragma unroll
    for (int r = 0; r < 4; ++r) ivr[r] = invs[wave * 16 + q * 4 + r];

    // softmax over k per C-row (row = px = q*4+r, col = k = t*16+pc).
    // Max-less: |logit| <= ||w_k|| ~ 1.13, exp range [0.32, 3.1] -- safe and
    // mathematically identical to the shifted form.
#pragma unroll
    for (int r = 0; r < 4; ++r) {
      float e[4], sm = 0.f;
#pragma unroll
      for (int t = 0; t < 4; ++t) {
        e[t] = __expf(acc1[t][r] * ivr[r]);
        sm += e[t];
      }
      sm += __shfl_xor(sm, 1);
      sm += __shfl_xor(sm, 2);
      sm += __shfl_xor(sm, 4);
      sm += __shfl_xor(sm, 8);
      float si = 1.f / sm;
#pragma unroll
      for (int t = 0; t < 4; ++t) {
        float av = e[t] * si;                 // plain a
        asr[t] += av;
        as_[(t * 16 + pc) * AS + wave * 16 + q * 4 + r] = f2b1(av * ivr[r]);
      }
    }
    __syncthreads();                          // xb + a_s complete

    // GEMM2: vlad acc += a_s[k][p] * xb[d][p], all from LDS (b128 frags,
    // xb reads XOR-deswizzled: row&7 == pc&7 on both write and read sides)
#pragma unroll
    for (int c = 0; c < 2; ++c) {             // px-chunks of 32
      short8 af2[4];
#pragma unroll
      for (int t = 0; t < 4; ++t)
        af2[t] = *(const short8*)&as_[(t * 16 + pc) * AS + c * 32 + q * 8];
#pragma unroll
      for (int s2 = 0; s2 < 8; ++s2) {
        const int row = wave * 128 + s2 * 16 + pc;
        short8 bf2 = *(const short8*)&xb[row * XS + ((c * 32 + q * 8) ^ rdxor)];
#pragma unroll
        for (int t = 0; t < 4; ++t)
          acc2[t][s2] = __builtin_amdgcn_mfma_f32_16x16x32_bf16(
              af2[t], bf2, acc2[t][s2], 0, 0, 0);
      }
    }
  }

  // epilogue: asum atomics + vpart bf16 stores
#pragma unroll
  for (int t = 0; t < 4; ++t) {
    float v = asr[t];
    v += __shfl_xor(v, 16);
    v += __shfl_xor(v, 32);
    if (q == 0) atomicAdd(&asum[n * Kk + t * 16 + pc], v);
  }
  short* vb = vpart + ((size_t)(seg * Nn + n) * Kk) * Dd;
#pragma unroll
  for (int t = 0; t < 4; ++t)
#pragma unroll
    for (int s2 = 0; s2 < 8; ++s2)
#pragma unroll
      for (int r = 0; r < 4; ++r)
        vb[(size_t)(t * 16 + q * 4 + r) * Dd + wave * 128 + s2 * 16 + pc] =
            f2b1(acc2[t][s2][r]);
}

// ---------------------------------------------------------------------------
// K2: combine 16 bf16 partials, subtract asum*centroid, intra-normalize,
// fold global 1/sqrt(K)=0.125 (rows are unit-norm after intra-normalization,
// so the global L2 norm is exactly sqrt(K)). grid: Nn*Kk blocks x 128 thr.
// ---------------------------------------------------------------------------
__global__ __launch_bounds__(128) void k_intra(
    const short* __restrict__ vpart, const float* __restrict__ asum,
    const float* __restrict__ cent, float* __restrict__ out)
{
  __shared__ float red[2];
  const int nk = blockIdx.x;
  const int n = nk >> 6, k = nk & 63;
  const int tid = threadIdx.x;
  const int d = tid * 4;

  float4 v = {0.f, 0.f, 0.f, 0.f};
#pragma unroll
  for (int ps = 0; ps < SEG; ++ps) {
    short4v t = *(const short4v*)&vpart[((size_t)(ps * Nn + n) * Kk + k) * Dd + d];
    v.x += b2f(t[0]); v.y += b2f(t[1]); v.z += b2f(t[2]); v.w += b2f(t[3]);
  }
  float s = asum[n * Kk + k];
  float4 c = *(const float4*)&cent[(size_t)k * Dd + d];
  v.x -= s * c.x; v.y -= s * c.y; v.z -= s * c.z; v.w -= s * c.w;

  float qq = v.x * v.x + v.y * v.y + v.z * v.z + v.w * v.w;
#pragma unroll
  for (int off = 32; off; off >>= 1) qq += __shfl_down(qq, off);
  if ((tid & 63) == 0) red[tid >> 6] = qq;
  __syncthreads();
  float norm = sqrtf(red[0] + red[1]);
  float r = 0.125f / fmaxf(norm, EPSF);   // intra-norm * global 1/sqrt(64)
  v.x *= r; v.y *= r; v.z *= r; v.w *= r;
  *(float4*)&out[(size_t)n * (Kk * Dd) + (size_t)k * Dd + d] = v;
}

extern "C" void kernel_launch(void* const* d_in, const int* in_sizes, int n_in,
                              void* d_out, int out_size, void* d_ws, size_t ws_size,
                              hipStream_t stream) {
  (void)in_sizes; (void)n_in; (void)out_size; (void)ws_size;
  const float* x    = (const float*)d_in[0];   // [N,D,H,W]
  const float* w    = (const float*)d_in[1];   // [K,D]
  const float* cent = (const float*)d_in[2];   // [K,D]
  float* out = (float*)d_out;

  // ws: asum f32[2048] | vpart bf16 [SEG*N*K*D] (33.5 MB) | wp bf16
  float* asum  = (float*)d_ws;
  short* vpart = (short*)(asum + Nn * Kk);
  short* wpk   = vpart + (size_t)SEG * Nn * Kk * Dd;

  k_wpack<<<4, 256, 0, stream>>>(w, asum, wpk);
  k_fused<<<Nn * SEG, 256, 0, stream>>>(x, wpk, asum, vpart);
  k_intra<<<Nn * Kk, 128, 0, stream>>>(vpart, asum, cent, out);
}